// Round 17
// baseline (318.605 us; speedup 1.0000x reference)
//
#include <hip/hip_runtime.h>
#include <hip/hip_bf16.h>

#define NN 50000
#define INF 256
#define NH 8
#define OUTF 64
#define NC 512
#define NGB 3128            // ceil(50048/16) fused blocks
#define EPB 8192            // edges per sort block
#define NBK 391             // buckets: node>>7, 50000/128
#define NBX 12501           // xbar block count

typedef __attribute__((ext_vector_type(8))) short bf16x8;
typedef __attribute__((ext_vector_type(4))) float f32x4;
typedef __attribute__((ext_vector_type(2))) float v2f;
typedef __attribute__((ext_vector_type(8))) float f32x8;

__device__ __forceinline__ unsigned short f2bf(float f){
  unsigned u = __float_as_uint(f);
  u += 0x7FFFu + ((u>>16)&1u);
  return (unsigned short)(u>>16);
}

// ---------- atil[h][f] = sum_o W[h*64+o][f] * a_r[h][o]  (runs FIRST; zeroes cursors)
__global__ void k_atil(const float* __restrict__ W, const float* __restrict__ As,
                       float* __restrict__ atil, int* __restrict__ cursor){
  const int h = blockIdx.x, f = threadIdx.x;
  if (h==0 && f==0){ cursor[0]=0; cursor[1]=0; }
  float s = 0.f;
  for (int o=0;o<64;o++) s += W[((long)h*64+o)*INF + f] * As[h*128 + 64 + o];
  atil[h*256 + f] = s;
}

// ---------- fused front-end: prep_w | bhist | xbar (atil from prior kernel)
__global__ __launch_bounds__(256) void k_front(const float* __restrict__ x,
                                               const float* __restrict__ W,
                                               unsigned short* __restrict__ Wt,
                                               const float* __restrict__ atil,
                                               unsigned short* __restrict__ xb,
                                               float* __restrict__ eAr,
                                               const int* __restrict__ src,
                                               int* __restrict__ M,
                                               int E, int NB){
  __shared__ int hh[NBK];
  const int tid = threadIdx.x;
  const int bid = blockIdx.x;
  if (bid < 8){
    const int r = tid>>2, cb = (tid&3)*64;
    char* tile = (char*)(Wt + (size_t)bid*16384);
    const float* Wr = W + ((long)bid*64 + r)*INF;
#pragma unroll
    for (int i=0;i<16;i++){
      int c = cb + i*4;
      float4 v = *(const float4*)(Wr + c);
      ushort4 b; b.x=f2bf(v.x); b.y=f2bf(v.y); b.z=f2bf(v.z); b.w=f2bf(v.w);
      int addr = r*512 + ((((c>>3) ^ (r&7)))<<4) + ((c&7)<<1);
      *(ushort4*)(tile + addr) = b;
    }
    return;
  }
  if (bid < 8+NB){
    const int b = bid-8;
    for (int i=tid;i<NBK;i+=256) hh[i]=0;
    __syncthreads();
    const int base = b*EPB;
    const int lim = min(E-base, EPB);
    for (int i=tid;i<lim;i+=256) atomicAdd(&hh[src[base+i]>>7], 1);
    __syncthreads();
    for (int i=tid;i<NBK;i+=256) M[(long)i*NB + b] = hh[i];
    return;
  }
  const int w = tid>>6, l = tid&63;
  const long n = (long)(bid-8-NB)*4 + w;
  if (n > NN) return;
  if (n == NN){
    uint2 z; z.x=0; z.y=0;
    *(uint2*)((char*)xb + (size_t)n*512 + l*8) = z;
    if (l < 8) eAr[n*NH + l] = 0.f;
    return;
  }
  float4 v = *(const float4*)(x + n*INF + l*4);
  uint2 d;
  d.x = (unsigned)f2bf(v.x) | ((unsigned)f2bf(v.y)<<16);
  d.y = (unsigned)f2bf(v.z) | ((unsigned)f2bf(v.w)<<16);
  *(uint2*)((char*)xb + (size_t)n*512 + l*8) = d;
  float p[8];
#pragma unroll
  for (int h=0;h<8;h++){
    float4 a = *(const float4*)(atil + h*256 + l*4);
    p[h] = v.x*a.x + v.y*a.y + v.z*a.z + v.w*a.w;
  }
#pragma unroll
  for (int off=1; off<64; off<<=1){
#pragma unroll
    for (int h=0;h<8;h++) p[h] += __shfl_xor(p[h], off, 64);
  }
  if (l < 8){
    float e = p[0];
#pragma unroll
    for (int h=1;h<8;h++) if (l==h) e = p[h];
    eAr[n*NH + l] = __expf(e);
  }
}

// per-bucket scan over blocks + cursor-allocated bucket base folded into M
__global__ __launch_bounds__(256) void k_bscan(int* __restrict__ M,
                                               int* __restrict__ bOff,
                                               int* __restrict__ bEnd,
                                               int* __restrict__ cursor, int NB){
  __shared__ int lds[256];
  __shared__ int sb;
  const int k = blockIdx.x, tid = threadIdx.x;
  int v = (tid<NB) ? M[(long)k*NB+tid] : 0;
  const int orig = v;
  lds[tid]=v; __syncthreads();
  for (int off=1; off<256; off<<=1){
    int a = (tid>=off)? lds[tid-off] : 0;
    __syncthreads(); lds[tid]+=a; __syncthreads();
  }
  if (tid==255){
    int tot = lds[255];
    int base = atomicAdd(&cursor[0], tot);
    sb = base;
    bOff[k] = base;
    bEnd[k] = base + tot;
  }
  __syncthreads();
  if (tid<NB) M[(long)k*NB+tid] = sb + lds[tid]-orig;
}

// bucket scatter of (src,dst) via LDS cursors — u32 payload: dst<<7 | src&127
__global__ __launch_bounds__(256) void k_bscat(const int* __restrict__ src,
                                               const int* __restrict__ dst,
                                               const int* __restrict__ M,
                                               unsigned* __restrict__ ebuf,
                                               int E, int NB){
  __shared__ int cur[NBK];
  const int tid = threadIdx.x, b = blockIdx.x;
  for (int i=tid;i<NBK;i+=256) cur[i] = M[(long)i*NB + b];
  __syncthreads();
  const int base = b*EPB;
  const int lim = min(E-base, EPB);
  for (int i=tid;i<lim;i+=256){
    int s = src[base+i], d = dst[base+i];
    int p = atomicAdd(&cur[s>>7], 1);
    ebuf[p] = ((unsigned)d<<7) | (unsigned)(s&127);
  }
}

// fused: per-bucket hist + padded scan + cursor alloc + row ranges + scatter + padfill
__global__ __launch_bounds__(256) void k_bcnt_final(const unsigned* __restrict__ ebuf,
                                                    const int* __restrict__ bOff,
                                                    const int* __restrict__ bEnd,
                                                    int* __restrict__ rbeg,
                                                    int* __restrict__ rend,
                                                    int* __restrict__ col,
                                                    int* __restrict__ cursor){
  __shared__ int h[128];
  __shared__ int s[128];
  __shared__ int cur[128];
  __shared__ int pend[128];
  __shared__ int sb;
  const int k = blockIdx.x, tid = threadIdx.x;
  if (tid<128) h[tid]=0;
  __syncthreads();
  const int beg = bOff[k], end = bEnd[k];
  for (int i=beg+tid; i<end; i+=256)
    atomicAdd(&h[(int)(ebuf[i] & 127u)], 1);
  __syncthreads();
  int pc = 0;
  if (tid<128){
    pc = (h[tid]+7)&~7;
    s[tid] = pc;
  }
  __syncthreads();
  for (int off=1; off<128; off<<=1){
    int a = (tid>=off && tid<128)? s[tid-off] : 0;
    __syncthreads();
    if (tid<128) s[tid] += a;
    __syncthreads();
  }
  if (tid==0){
    sb = atomicAdd(&cursor[1], s[127]);
  }
  __syncthreads();
  if (tid<128){
    int rp = sb + s[tid] - pc;
    rbeg[(k<<7)+tid] = rp;
    rend[(k<<7)+tid] = rp + pc;
    cur[tid] = rp;
    pend[tid] = rp + pc;
  }
  __syncthreads();
  for (int i=beg+tid; i<end; i+=256){
    unsigned e = ebuf[i];
    int p = atomicAdd(&cur[e & 127u], 1);
    col[p] = (int)(e>>7);
  }
  __syncthreads();
  if (tid<128){
    for (int i=cur[tid]; i<pend[tid]; i++) col[i] = NN;  // sentinel
  }
}

// ---------------- FUSED aggregation + per-head GEMM (g-tile lives in LDS)
// block: 512 threads (8 waves) = 16 nodes.
// Phase 1: proven half-row gather, 4 sequential tasks/wave -> LDS g-tile
//   gt layout: [r(16)][h(8)][512B seg], seg byte = (fh*256 + l*4) ^ ((r&7)<<4)
// Phase 2: wave w = head w; MFMA 16x64 per head, A from gt (same XOR), B from Wt image.
__global__ __launch_bounds__(512) void k_aggr_gemm(const int* __restrict__ rbeg,
                                                   const int* __restrict__ rend,
                                                   const int* __restrict__ col,
                                                   const unsigned short* __restrict__ xb,
                                                   const float* __restrict__ eAr,
                                                   const unsigned short* __restrict__ Wt,
                                                   float* __restrict__ out){
  __shared__ char gt[16*4096];
  __shared__ float sden[16][8];
  const int tid = threadIdx.x, l = tid&63, wid = tid>>6;
  const long nb = (long)blockIdx.x*16;
  const long l4 = (long)l*4;
  const int lw = l&7;

  for (int t=0; t<4; t++){
    const int task = wid*4 + t;        // 0..31
    const int r  = task>>1, fh = task&1;
    const long n = nb + r;
    const int beg = __builtin_amdgcn_readfirstlane(rbeg[n]);
    const int end = __builtin_amdgcn_readfirstlane(rend[n]);
    const char* xbp = (const char*)xb + fh*256;
    v2f acc[8] = {};
    float dnl = 0.f;
    for (int i=beg; i<end; i+=8){
      int cc[8];
#pragma unroll
      for (int e=0;e<8;e++) cc[e] = __builtin_amdgcn_readfirstlane(col[i+e]);
      unsigned q[8];
#pragma unroll
      for (int e=0;e<8;e++) q[e] = *(const unsigned*)(xbp + (size_t)cc[e]*512 + l4);
      float wl[8];
#pragma unroll
      for (int e=0;e<8;e++) wl[e] = eAr[(size_t)cc[e]*NH + lw];
#pragma unroll
      for (int e=0;e<8;e++) dnl += wl[e];
#pragma unroll
      for (int e=0;e<8;e++){
        f32x8 wv8 = *(const f32x8*)(eAr + (size_t)cc[e]*NH);
        v2f f01;
        f01.x = __uint_as_float(q[e]<<16);
        f01.y = __uint_as_float(q[e]&0xffff0000u);
#pragma unroll
        for (int h=0;h<8;h++){
          v2f w2; w2.x = wv8[h]; w2.y = wv8[h];
          acc[h] = __builtin_elementwise_fma(w2, f01, acc[h]);
        }
      }
    }
    // swizzled LDS write: 4B per head, bank-spread by XOR (2-way max = free)
    char* seg = gt + r*4096;
    const int boff = (fh*256 + l*4) ^ ((r&7)<<4);
#pragma unroll
    for (int h=0;h<8;h++){
      unsigned d = (unsigned)f2bf(acc[h].x) | ((unsigned)f2bf(acc[h].y)<<16);
      *(unsigned*)(seg + h*512 + boff) = d;
    }
    if (fh==0 && l<8) sden[r][l] = dnl;
  }
  __syncthreads();

  // Phase 2: per-head GEMM. wave wid = head.
  const int h = wid;
  const char* Wh = (const char*)Wt + (size_t)h*32768;
  const int row = l&15;
  f32x4 acc2[4] = {};
  for (int ks=0; ks<8; ks++){
    const int ck = ks*4 + (l>>4);
    bf16x8 af = *(const bf16x8*)(gt + row*4096 + h*512 + ((ck ^ (row&7))<<4));
#pragma unroll
    for (int ct=0; ct<4; ct++){
      const int c = ct*16 + row;
      bf16x8 bfr = *(const bf16x8*)(Wh + c*512 + ((ck ^ (c&7))<<4));
      acc2[ct] = __builtin_amdgcn_mfma_f32_16x16x32_bf16(af, bfr, acc2[ct], 0,0,0);
    }
  }
  float lv[4];
#pragma unroll
  for (int j=0;j<4;j++){
    float dv = sden[(l>>4)*4 + j][h];
    lv[j] = dv>0.f ? 1.f/dv : 0.f;
  }
#pragma unroll
  for (int ct=0; ct<4; ct++){
#pragma unroll
    for (int j=0;j<4;j++){
      long gr = nb + (l>>4)*4 + j;
      if (gr < NN){
        float v = acc2[ct][j] * lv[j];
        out[gr*NC + h*64 + ct*16 + row] = v>0.f ? v : expm1f(v);
      }
    }
  }
}

extern "C" void kernel_launch(void* const* d_in, const int* in_sizes, int n_in,
                              void* d_out, int out_size, void* d_ws, size_t ws_size,
                              hipStream_t stream){
  const float* x   = (const float*)d_in[0];
  const int*   src = (const int*)d_in[1];
  const int*   dst = (const int*)d_in[2];
  const float* Ws  = (const float*)d_in[3];
  const float* Av  = (const float*)d_in[4];
  const int E = in_sizes[1];
  const int NB = (E + EPB - 1) / EPB;

  char* ws = (char*)d_ws;
  size_t off = 0;
  auto alloc = [&](size_t bytes)->void*{
    void* p = ws + off; off += (bytes + 255) & ~(size_t)255; return p;
  };
  unsigned short* xb   = (unsigned short*)alloc((size_t)50048*512);
  float* eAr           = (float*)alloc((size_t)50048*NH*4);
  float* atil          = (float*)alloc(8*256*4);
  unsigned short* Wt   = (unsigned short*)alloc((size_t)8*32768);
  int*   rbeg          = (int*)alloc(50304*4);
  int*   rend          = (int*)alloc(50304*4);
  int*   M             = (int*)alloc((size_t)NBK*256*4);
  int*   bOff          = (int*)alloc(512*4);
  int*   bEnd          = (int*)alloc(512*4);
  int*   cursor        = (int*)alloc(256);
  int*   col           = (int*)alloc(((size_t)E + 8*50048 + 64)*4);
  unsigned* ebuf       = (unsigned*)alloc((size_t)E*4);

  k_atil<<<8,256,0,stream>>>(Ws, Av, atil, cursor);
  k_front<<<8+NB+NBX,256,0,stream>>>(x, Ws, Wt, atil, xb, eAr, src, M, E, NB);
  k_bscan<<<NBK,256,0,stream>>>(M, bOff, bEnd, cursor, NB);
  k_bscat<<<NB,256,0,stream>>>(src, dst, M, ebuf, E, NB);
  k_bcnt_final<<<NBK,256,0,stream>>>(ebuf, bOff, bEnd, rbeg, rend, col, cursor);
  k_aggr_gemm<<<NGB,512,0,stream>>>(rbeg, rend, col, xb, eAr, Wt, (float*)d_out);
}

// Round 18
// 287.932 us; speedup vs baseline: 1.1065x; 1.1065x over previous
//
#include <hip/hip_runtime.h>
#include <hip/hip_bf16.h>

#define NN 50000
#define INF 256
#define NH 8
#define OUTF 64
#define NC 512
#define NGB 3128            // ceil(50048/16) fused blocks
#define EPB 8192            // edges per sort block
#define NBK 391             // buckets: node>>7, 50000/128
#define NBX 12501           // xbar block count

typedef __attribute__((ext_vector_type(8))) short bf16x8;
typedef __attribute__((ext_vector_type(4))) float f32x4;
typedef __attribute__((ext_vector_type(2))) float v2f;
typedef __attribute__((ext_vector_type(8))) float f32x8;

__device__ __forceinline__ unsigned short f2bf(float f){
  unsigned u = __float_as_uint(f);
  u += 0x7FFFu + ((u>>16)&1u);
  return (unsigned short)(u>>16);
}

// ---------- atil[h][f] = sum_o W[h*64+o][f] * a_r[h][o]  (runs FIRST; zeroes cursors)
__global__ void k_atil(const float* __restrict__ W, const float* __restrict__ As,
                       float* __restrict__ atil, int* __restrict__ cursor){
  const int h = blockIdx.x, f = threadIdx.x;
  if (h==0 && f==0){ cursor[0]=0; cursor[1]=0; }
  float s = 0.f;
  for (int o=0;o<64;o++) s += W[((long)h*64+o)*INF + f] * As[h*128 + 64 + o];
  atil[h*256 + f] = s;
}

// ---------- fused front-end: prep_w | bhist | xbar (atil from prior kernel)
__global__ __launch_bounds__(256) void k_front(const float* __restrict__ x,
                                               const float* __restrict__ W,
                                               unsigned short* __restrict__ Wt,
                                               const float* __restrict__ atil,
                                               unsigned short* __restrict__ xb,
                                               float* __restrict__ eAr,
                                               const int* __restrict__ src,
                                               int* __restrict__ M,
                                               int E, int NB){
  __shared__ int hh[NBK];
  const int tid = threadIdx.x;
  const int bid = blockIdx.x;
  if (bid < 8){
    const int r = tid>>2, cb = (tid&3)*64;
    char* tile = (char*)(Wt + (size_t)bid*16384);
    const float* Wr = W + ((long)bid*64 + r)*INF;
#pragma unroll
    for (int i=0;i<16;i++){
      int c = cb + i*4;
      float4 v = *(const float4*)(Wr + c);
      ushort4 b; b.x=f2bf(v.x); b.y=f2bf(v.y); b.z=f2bf(v.z); b.w=f2bf(v.w);
      int addr = r*512 + ((((c>>3) ^ (r&7)))<<4) + ((c&7)<<1);
      *(ushort4*)(tile + addr) = b;
    }
    return;
  }
  if (bid < 8+NB){
    const int b = bid-8;
    for (int i=tid;i<NBK;i+=256) hh[i]=0;
    __syncthreads();
    const int base = b*EPB;
    const int lim = min(E-base, EPB);
    for (int i=tid;i<lim;i+=256) atomicAdd(&hh[src[base+i]>>7], 1);
    __syncthreads();
    for (int i=tid;i<NBK;i+=256) M[(long)i*NB + b] = hh[i];
    return;
  }
  const int w = tid>>6, l = tid&63;
  const long n = (long)(bid-8-NB)*4 + w;
  if (n > NN) return;
  if (n == NN){
    uint2 z; z.x=0; z.y=0;
    *(uint2*)((char*)xb + (size_t)n*512 + l*8) = z;
    if (l < 8) eAr[n*NH + l] = 0.f;
    return;
  }
  float4 v = *(const float4*)(x + n*INF + l*4);
  uint2 d;
  d.x = (unsigned)f2bf(v.x) | ((unsigned)f2bf(v.y)<<16);
  d.y = (unsigned)f2bf(v.z) | ((unsigned)f2bf(v.w)<<16);
  *(uint2*)((char*)xb + (size_t)n*512 + l*8) = d;
  float p[8];
#pragma unroll
  for (int h=0;h<8;h++){
    float4 a = *(const float4*)(atil + h*256 + l*4);
    p[h] = v.x*a.x + v.y*a.y + v.z*a.z + v.w*a.w;
  }
#pragma unroll
  for (int off=1; off<64; off<<=1){
#pragma unroll
    for (int h=0;h<8;h++) p[h] += __shfl_xor(p[h], off, 64);
  }
  if (l < 8){
    float e = p[0];
#pragma unroll
    for (int h=1;h<8;h++) if (l==h) e = p[h];
    eAr[n*NH + l] = __expf(e);
  }
}

// per-bucket scan over blocks + cursor-allocated bucket base folded into M
__global__ __launch_bounds__(256) void k_bscan(int* __restrict__ M,
                                               int* __restrict__ bOff,
                                               int* __restrict__ bEnd,
                                               int* __restrict__ cursor, int NB){
  __shared__ int lds[256];
  __shared__ int sb;
  const int k = blockIdx.x, tid = threadIdx.x;
  int v = (tid<NB) ? M[(long)k*NB+tid] : 0;
  const int orig = v;
  lds[tid]=v; __syncthreads();
  for (int off=1; off<256; off<<=1){
    int a = (tid>=off)? lds[tid-off] : 0;
    __syncthreads(); lds[tid]+=a; __syncthreads();
  }
  if (tid==255){
    int tot = lds[255];
    int base = atomicAdd(&cursor[0], tot);
    sb = base;
    bOff[k] = base;
    bEnd[k] = base + tot;
  }
  __syncthreads();
  if (tid<NB) M[(long)k*NB+tid] = sb + lds[tid]-orig;
}

// bucket scatter of (src,dst) via LDS cursors — u32 payload: dst<<7 | src&127
__global__ __launch_bounds__(256) void k_bscat(const int* __restrict__ src,
                                               const int* __restrict__ dst,
                                               const int* __restrict__ M,
                                               unsigned* __restrict__ ebuf,
                                               int E, int NB){
  __shared__ int cur[NBK];
  const int tid = threadIdx.x, b = blockIdx.x;
  for (int i=tid;i<NBK;i+=256) cur[i] = M[(long)i*NB + b];
  __syncthreads();
  const int base = b*EPB;
  const int lim = min(E-base, EPB);
  for (int i=tid;i<lim;i+=256){
    int s = src[base+i], d = dst[base+i];
    int p = atomicAdd(&cur[s>>7], 1);
    ebuf[p] = ((unsigned)d<<7) | (unsigned)(s&127);
  }
}

// fused: per-bucket hist + padded scan + cursor alloc + row ranges + scatter + padfill
__global__ __launch_bounds__(256) void k_bcnt_final(const unsigned* __restrict__ ebuf,
                                                    const int* __restrict__ bOff,
                                                    const int* __restrict__ bEnd,
                                                    int* __restrict__ rbeg,
                                                    int* __restrict__ rend,
                                                    int* __restrict__ col,
                                                    int* __restrict__ cursor){
  __shared__ int h[128];
  __shared__ int s[128];
  __shared__ int cur[128];
  __shared__ int pend[128];
  __shared__ int sb;
  const int k = blockIdx.x, tid = threadIdx.x;
  if (tid<128) h[tid]=0;
  __syncthreads();
  const int beg = bOff[k], end = bEnd[k];
  for (int i=beg+tid; i<end; i+=256)
    atomicAdd(&h[(int)(ebuf[i] & 127u)], 1);
  __syncthreads();
  int pc = 0;
  if (tid<128){
    pc = (h[tid]+7)&~7;
    s[tid] = pc;
  }
  __syncthreads();
  for (int off=1; off<128; off<<=1){
    int a = (tid>=off && tid<128)? s[tid-off] : 0;
    __syncthreads();
    if (tid<128) s[tid] += a;
    __syncthreads();
  }
  if (tid==0){
    sb = atomicAdd(&cursor[1], s[127]);
  }
  __syncthreads();
  if (tid<128){
    int rp = sb + s[tid] - pc;
    rbeg[(k<<7)+tid] = rp;
    rend[(k<<7)+tid] = rp + pc;
    cur[tid] = rp;
    pend[tid] = rp + pc;
  }
  __syncthreads();
  for (int i=beg+tid; i<end; i+=256){
    unsigned e = ebuf[i];
    int p = atomicAdd(&cur[e & 127u], 1);
    col[p] = (int)(e>>7);
  }
  __syncthreads();
  if (tid<128){
    for (int i=cur[tid]; i<pend[tid]; i++) col[i] = NN;  // sentinel
  }
}

// ---------------- FUSED aggregation + per-head GEMM, 16 waves/block
// Phase 1: wave w gathers node nb+w FULL row (uint2, r8-proven loop) -> LDS
//   gt[r][h][512B], byte = (l*8) ^ ((r&7)<<4)
// Phase 2: wave w -> head w>>1, column-half w&1 (32 cols); A from gt, B from Wt.
__global__ __launch_bounds__(1024) void k_aggr_gemm(const int* __restrict__ rbeg,
                                                    const int* __restrict__ rend,
                                                    const int* __restrict__ col,
                                                    const unsigned short* __restrict__ xb,
                                                    const float* __restrict__ eAr,
                                                    const unsigned short* __restrict__ Wt,
                                                    float* __restrict__ out){
  __shared__ char gt[16*4096];
  __shared__ float sden[16][8];
  const int tid = threadIdx.x, l = tid&63, wid = tid>>6;
  const long nb = (long)blockIdx.x*16;
  const long l8 = (long)l*8;
  const int lw = l&7;

  // ---- Phase 1: full-row gather, one node per wave
  {
    const int r = wid;
    const long n = nb + r;
    const int beg = __builtin_amdgcn_readfirstlane(rbeg[n]);
    const int end = __builtin_amdgcn_readfirstlane(rend[n]);
    const char* xbp = (const char*)xb;
    v2f acc[8][2] = {};
    float dnl = 0.f;
    for (int i=beg; i<end; i+=8){
      int cc[8];
#pragma unroll
      for (int e=0;e<8;e++) cc[e] = __builtin_amdgcn_readfirstlane(col[i+e]);
      uint2 q[8];
#pragma unroll
      for (int e=0;e<8;e++) q[e] = *(const uint2*)(xbp + (size_t)cc[e]*512 + l8);
      float wl[8];
#pragma unroll
      for (int e=0;e<8;e++) wl[e] = eAr[(size_t)cc[e]*NH + lw];
#pragma unroll
      for (int e=0;e<8;e++) dnl += wl[e];
#pragma unroll
      for (int e=0;e<8;e++){
        f32x8 wv8 = *(const f32x8*)(eAr + (size_t)cc[e]*NH);
        v2f f01, f23;
        f01.x = __uint_as_float(q[e].x<<16);
        f01.y = __uint_as_float(q[e].x&0xffff0000u);
        f23.x = __uint_as_float(q[e].y<<16);
        f23.y = __uint_as_float(q[e].y&0xffff0000u);
#pragma unroll
        for (int h=0;h<8;h++){
          v2f w2; w2.x = wv8[h]; w2.y = wv8[h];
          acc[h][0] = __builtin_elementwise_fma(w2, f01, acc[h][0]);
          acc[h][1] = __builtin_elementwise_fma(w2, f23, acc[h][1]);
        }
      }
    }
    char* seg = gt + r*4096;
    const int boff = (int)(l8 ^ ((r&7)<<4));
#pragma unroll
    for (int h=0;h<8;h++){
      uint2 d;
      d.x = (unsigned)f2bf(acc[h][0].x) | ((unsigned)f2bf(acc[h][0].y)<<16);
      d.y = (unsigned)f2bf(acc[h][1].x) | ((unsigned)f2bf(acc[h][1].y)<<16);
      *(uint2*)(seg + h*512 + boff) = d;
    }
    if (l<8) sden[r][l] = dnl;
  }
  __syncthreads();

  // ---- Phase 2: wave -> (head, column-half)
  const int h = wid>>1;
  const int chalf = wid&1;
  const char* Wh = (const char*)Wt + (size_t)h*32768;
  const int row = l&15;
  f32x4 acc2[2] = {};
  for (int ks=0; ks<8; ks++){
    const int ck = ks*4 + (l>>4);
    bf16x8 af = *(const bf16x8*)(gt + row*4096 + h*512 + ((ck ^ (row&7))<<4));
#pragma unroll
    for (int ct=0; ct<2; ct++){
      const int c = chalf*32 + ct*16 + row;
      bf16x8 bfr = *(const bf16x8*)(Wh + c*512 + ((ck ^ (c&7))<<4));
      acc2[ct] = __builtin_amdgcn_mfma_f32_16x16x32_bf16(af, bfr, acc2[ct], 0,0,0);
    }
  }
  float lv[4];
#pragma unroll
  for (int j=0;j<4;j++){
    float dv = sden[(l>>4)*4 + j][h];
    lv[j] = dv>0.f ? 1.f/dv : 0.f;
  }
#pragma unroll
  for (int ct=0; ct<2; ct++){
#pragma unroll
    for (int j=0;j<4;j++){
      long gr = nb + (l>>4)*4 + j;
      if (gr < NN){
        float v = acc2[ct][j] * lv[j];
        out[gr*NC + h*64 + chalf*32 + ct*16 + row] = v>0.f ? v : expm1f(v);
      }
    }
  }
}

extern "C" void kernel_launch(void* const* d_in, const int* in_sizes, int n_in,
                              void* d_out, int out_size, void* d_ws, size_t ws_size,
                              hipStream_t stream){
  const float* x   = (const float*)d_in[0];
  const int*   src = (const int*)d_in[1];
  const int*   dst = (const int*)d_in[2];
  const float* Ws  = (const float*)d_in[3];
  const float* Av  = (const float*)d_in[4];
  const int E = in_sizes[1];
  const int NB = (E + EPB - 1) / EPB;

  char* ws = (char*)d_ws;
  size_t off = 0;
  auto alloc = [&](size_t bytes)->void*{
    void* p = ws + off; off += (bytes + 255) & ~(size_t)255; return p;
  };
  unsigned short* xb   = (unsigned short*)alloc((size_t)50048*512);
  float* eAr           = (float*)alloc((size_t)50048*NH*4);
  float* atil          = (float*)alloc(8*256*4);
  unsigned short* Wt   = (unsigned short*)alloc((size_t)8*32768);
  int*   rbeg          = (int*)alloc(50304*4);
  int*   rend          = (int*)alloc(50304*4);
  int*   M             = (int*)alloc((size_t)NBK*256*4);
  int*   bOff          = (int*)alloc(512*4);
  int*   bEnd          = (int*)alloc(512*4);
  int*   cursor        = (int*)alloc(256);
  int*   col           = (int*)alloc(((size_t)E + 8*50048 + 64)*4);
  unsigned* ebuf       = (unsigned*)alloc((size_t)E*4);

  k_atil<<<8,256,0,stream>>>(Ws, Av, atil, cursor);
  k_front<<<8+NB+NBX,256,0,stream>>>(x, Ws, Wt, atil, xb, eAr, src, M, E, NB);
  k_bscan<<<NBK,256,0,stream>>>(M, bOff, bEnd, cursor, NB);
  k_bscat<<<NB,256,0,stream>>>(src, dst, M, ebuf, E, NB);
  k_bcnt_final<<<NBK,256,0,stream>>>(ebuf, bOff, bEnd, rbeg, rend, col, cursor);
  k_aggr_gemm<<<NGB,1024,0,stream>>>(rbeg, rend, col, xb, eAr, Wt, (float*)d_out);
}